// Round 1
// baseline (148.095 us; speedup 1.0000x reference)
//
#include <hip/hip_runtime.h>
#include <math.h>

#define NPTS 131072
#define KCOMP 256
#define DIM 32
#define KF 576                    // 528 tight-packed quad + 32 linear + 16 pad
#define NREAL 560                 // real features; [560,576) is never touched
#define PSIF_BYTES 294912         // 9 chunks * 2048 granules * 16 B
#define WS_NEED (PSIF_BYTES + KCOMP * 4)

typedef __attribute__((ext_vector_type(8))) short short8;
typedef __attribute__((ext_vector_type(16))) float f32x16;

__device__ __forceinline__ unsigned short f2bf(float v) {
    unsigned u = __float_as_uint(v);
    u += 0x7fffu + ((u >> 16) & 1u);   // RNE
    return (unsigned short)(u >> 16);
}

// pack two f32 -> two bf16 (lo | hi<<16). RTN (+0x8000) + byte-perm: 3 ops.
__device__ __forceinline__ unsigned pkbf(float lo, float hi) {
#if __has_builtin(__builtin_amdgcn_perm)
    const unsigned a = __float_as_uint(hi) + 0x8000u;
    const unsigned b = __float_as_uint(lo) + 0x8000u;
    return __builtin_amdgcn_perm(a, b, 0x07060302u);
#else
    return (unsigned)f2bf(lo) | ((unsigned)f2bf(hi) << 16);
#endif
}

// async global->LDS DMA, 16 B/lane; LDS dest = wave-uniform base + lane*16.
__device__ __forceinline__ void dma16(const uint4* g, uint4* s) {
    __builtin_amdgcn_global_load_lds(
        (const __attribute__((address_space(1))) void*)g,
        (__attribute__((address_space(3))) void*)s, 16, 0, 0);
}

// LDS-only barrier: drain lgkmcnt but let global_load_lds (vmcnt) keep flying.
__device__ __forceinline__ void barrier_lds_only() {
    asm volatile("s_waitcnt lgkmcnt(0)\ns_barrier" ::: "memory");
}

// ---- compile-time feature decode: TIGHT triangular packing ----------------
// p in [0,528): (d,f) pairs, f>=d, row-major (row d has 32-d entries).
// p in [528,560): linear features (index p-528).
// p in [560,576): zero pad (skipped entirely: last chunk runs only 3 K16-steps).
constexpr int PfxT(int d) { return 32 * d - (d * (d - 1)) / 2; }
constexpr int rowT(int p) { int d = 0; while (d < 31 && PfxT(d + 1) <= p) ++d; return d; }
constexpr int colT(int p) { return rowT(p) + (p - PfxT(rowT(p))); }

template<int P, int J>
__device__ __forceinline__ float genOne(const float (&x)[DIM]) {
    constexpr int p = P + J;
    if constexpr (p >= NREAL) {
        return 0.f;
    } else if constexpr (p >= 528) {
        return x[p - 528];
    } else {
        constexpr int d = rowT(p);
        constexpr int f = colT(p);
        static_assert(d >= 0 && d < 32 && f >= d && f < 32, "bad feature map");
        return x[d] * x[f];
    }
}

// ---------------------------------------------------------------------------
// Precompute: Psi column k scattered into frag-ordered PsiF (bf16), kc2 fp32.
// ---------------------------------------------------------------------------
__global__ __launch_bounds__(256) void gmm_pre(
    const float* __restrict__ S,
    const float* __restrict__ centers,
    const float* __restrict__ weights,
    unsigned short* __restrict__ PsiF,
    float* __restrict__ kc2)
{
    __shared__ float Sl[DIM][DIM + 1];
    __shared__ float As[DIM][DIM + 1];
    __shared__ float cl[DIM], ml[DIM];
    __shared__ float red[256];

    const int k = blockIdx.x, tid = threadIdx.x;

    for (int idx = tid; idx < DIM * DIM; idx += 256)
        Sl[idx >> 5][idx & 31] = S[(size_t)k * DIM * DIM + idx];
    if (tid < DIM) cl[tid] = centers[k * DIM + tid];
    __syncthreads();

    // A = S S^T
    for (int idx = tid; idx < DIM * DIM; idx += 256) {
        const int d = idx >> 5, f = idx & 31;
        float a = 0.f;
#pragma unroll
        for (int e = 0; e < DIM; ++e) a = fmaf(Sl[d][e], Sl[f][e], a);
        As[d][f] = a;
    }
    __syncthreads();

    if (tid < DIM) {
        float mv = 0.f;
#pragma unroll
        for (int f = 0; f < DIM; ++f) mv = fmaf(As[tid][f], cl[f], mv);
        ml[tid] = mv;
    }
    __syncthreads();

    // scatter Psi column k into frag positions (reads As diag+upper, ml).
    // tight packing: p<528 -> (d,f) f>=d; 528..559 -> ml; pad never written.
    for (int p = tid; p < NREAL; p += 256) {
        float val;
        if (p < 528) {
            int d = 0, pr = 0;
            while (pr + (32 - d) <= p) { pr += (32 - d); ++d; }
            const int f = d + (p - pr);
            val = (f == d) ? -0.5f * As[d][d] : -As[d][f];
        } else {
            val = ml[p - 528];
        }
        const int c = p >> 6, kk = p & 63;
        const int s = kk >> 4, qq = (kk >> 3) & 1, j = kk & 7;
        const int ct = k >> 5, ll = qq * 32 + (k & 31);
        const int g = c * 2048 + (s * 8 + ct) * 64 + ll;
        PsiF[(size_t)g * 8 + j] = f2bf(val);
    }

    red[tid] = fabsf(weights[tid]);          // K == 256 == blockDim
    __syncthreads();                          // also fences As/ml reads above
    for (int off = 128; off > 0; off >>= 1) {
        if (tid < off) red[tid] += red[tid + off];
        __syncthreads();
    }
    const float wsum = red[0];

    // SPD Gaussian elimination: 1 barrier/step, logdet(A) = sum log(pivot_j).
    for (int j = 0; j < DIM - 1; ++j) {
        const float inv = 1.0f / As[j][j];
        for (int idx = tid; idx < DIM * DIM; idx += 256) {
            const int r = idx >> 5, c = idx & 31;
            if (r > j && c > j)
                As[r][c] = fmaf(-As[r][j] * inv, As[j][c], As[r][c]);
        }
        __syncthreads();
    }

    if (tid < DIM) red[tid] = __logf(As[tid][tid]);   // pivots > 0 (SPD)
    __syncthreads();
    if (tid == 0) {
        float sl = 0.f;
        for (int j = 0; j < DIM; ++j) sl += red[j];
        float cac = 0.f;
        for (int d2 = 0; d2 < DIM; ++d2) cac = fmaf(ml[d2], cl[d2], cac);
        kc2[k] = __logf(fabsf(weights[k])) - __logf(wsum + 1e-30f)
               + 0.5f * sl - 0.5f * cac;
    }
}

// ---------------------------------------------------------------------------
// Main MFMA kernel: A genned in LDS, B DMA'd double-buffered via
// global_load_lds (zero VGPR staging), 1 lgkm-only + 1 full barrier per chunk.
// 9 chunks; last chunk runs 3 K16-steps (48 real features), pad step skipped.
// ---------------------------------------------------------------------------
template<int P>
__device__ __forceinline__ void genQuad(const float (&x)[DIM], float* v) {
    v[0] = genOne<P, 0>(x);
    v[1] = genOne<P, 1>(x);
    v[2] = genOne<P, 2>(x);
    v[3] = genOne<P, 3>(x);
}

template<int C, int SS>
__device__ __forceinline__ void genSite(const float (&x)[DIM], uint4* sA4,
                                        int rbg, int r32) {
    float v[8];
    genQuad<C * 64 + SS * 8>(x, v);
    genQuad<C * 64 + SS * 8 + 4>(x, v + 4);
    uint4 u;
    u.x = pkbf(v[0], v[1]);
    u.y = pkbf(v[2], v[3]);
    u.z = pkbf(v[4], v[5]);
    u.w = pkbf(v[6], v[7]);
    sA4[(SS >> 1) * 256 + rbg * 64 + (SS & 1) * 32 + r32] = u;
}

template<int C>
__device__ __forceinline__ void doChunk(const float (&x)[DIM],
    uint4* sA4, uint4* sB4, const uint4* __restrict__ PsiF4,
    f32x16 (&acc0)[4], f32x16 (&acc1)[4],
    int l, int w, int q, int rbg, int r32, int r0, int c0)
{
    constexpr int NS  = (C < 8) ? 4 : 3;                   // K16-steps here
    constexpr int NSn = (C < 7) ? 4 : ((C == 7) ? 3 : 0);  // next chunk's

    if constexpr (C > 0) barrier_lds_only();   // sA(c-1)/buf[(c-1)&1] readers done
    // gen A(c) -> sA
    if (q == 0) {
        genSite<C, 0>(x, sA4, rbg, r32);
        genSite<C, 2>(x, sA4, rbg, r32);
        if constexpr (NS >= 3) genSite<C, 4>(x, sA4, rbg, r32);
        if constexpr (NS == 4) genSite<C, 6>(x, sA4, rbg, r32);
    } else {
        genSite<C, 1>(x, sA4, rbg, r32);
        genSite<C, 3>(x, sA4, rbg, r32);
        if constexpr (NS >= 3) genSite<C, 5>(x, sA4, rbg, r32);
        if constexpr (NS == 4) genSite<C, 7>(x, sA4, rbg, r32);
    }
    __syncthreads();   // sA ready; drains DMA(c) (issued a full chunk ago)

    // issue DMA for chunk c+1 into the other buffer; drained at next full
    // barrier with MFMA(c)+gen(c+1) of cover.
    if constexpr (NSn > 0) {
        const uint4* src = PsiF4 + (C + 1) * 2048 + w * 64 + l;
        uint4* dst = sB4 + ((C + 1) & 1) * 2048 + w * 64 + l;
#pragma unroll
        for (int i = 0; i < NSn * 2; ++i) dma16(src + i * 256, dst + i * 256);
    }

    const uint4* bb = sB4 + (C & 1) * 2048;
#pragma unroll
    for (int s = 0; s < NS; ++s) {
        short8 a0 = __builtin_bit_cast(short8, sA4[(s * 4 + r0) * 64 + l]);
        short8 a1 = __builtin_bit_cast(short8, sA4[(s * 4 + r0 + 1) * 64 + l]);
#pragma unroll
        for (int j = 0; j < 4; ++j) {
            short8 b = __builtin_bit_cast(short8, bb[(s * 8 + c0 + j) * 64 + l]);
            acc0[j] = __builtin_amdgcn_mfma_f32_32x32x16_bf16(a0, b, acc0[j], 0, 0, 0);
            acc1[j] = __builtin_amdgcn_mfma_f32_32x32x16_bf16(a1, b, acc1[j], 0, 0, 0);
        }
    }
}

__device__ __forceinline__ void epiHalf(const f32x16 (&acc)[4], const float (&kcv)[4],
    int rblock, int l, int whalf, float (*sM)[2], float (*sS)[2])
{
#pragma unroll
    for (int rg = 0; rg < 16; ++rg) {
        float vals[4], m = -INFINITY;
#pragma unroll
        for (int j = 0; j < 4; ++j) { vals[j] = acc[j][rg] + kcv[j]; m = fmaxf(m, vals[j]); }
#pragma unroll
        for (int mask = 1; mask < 32; mask <<= 1) m = fmaxf(m, __shfl_xor(m, mask, 64));
        float sv = 0.f;
#pragma unroll
        for (int j = 0; j < 4; ++j) sv += __expf(vals[j] - m);
#pragma unroll
        for (int mask = 1; mask < 32; mask <<= 1) sv += __shfl_xor(sv, mask, 64);
        if ((l & 31) == 0) {
            const int R = rblock * 32 + (rg & 3) + 8 * (rg >> 2) + 4 * (l >> 5);
            sM[R][whalf] = m; sS[R][whalf] = sv;
        }
    }
}

__global__ __launch_bounds__(256, 2) void gmm_mfma(
    const float* __restrict__ points,
    const unsigned short* __restrict__ PsiF,
    const float* __restrict__ kc2,
    const float* __restrict__ thr,
    float* __restrict__ out)
{
    __shared__ uint4 sA4[1024];          // 16 KB: frag-ordered A chunk
    __shared__ uint4 sB4[4096];          // 64 KB: B double buffer (2 x 32 KB)
    // epilogue scratch overlaid on sA4 (after a barrier): sM 1 KB, sS 1 KB
    float (*sM)[2] = (float (*)[2])sA4;
    float (*sS)[2] = (float (*)[2])(sA4 + 64);

    const int t = threadIdx.x;
    const int w = t >> 6, l = t & 63;
    const int row = t & 127, q = t >> 7;           // gen role: 2 threads/row
    const int rbg = row >> 5, r32 = row & 31;
    const int r0 = (w >> 1) * 2, c0 = (w & 1) * 4; // mfma wave tile: 64r x 128c

    const uint4* PsiF4 = (const uint4*)PsiF;

    // prologue DMA: chunk 0's B into buffer 0 (covered by x-load + init + gen)
    {
        const uint4* src = PsiF4 + w * 64 + l;
        uint4* dst = sB4 + w * 64 + l;
#pragma unroll
        for (int i = 0; i < 8; ++i) dma16(src + i * 256, dst + i * 256);
    }

    float x[DIM];
    const float4* px = (const float4*)(points + ((size_t)blockIdx.x * 128 + row) * DIM);
#pragma unroll
    for (int j2 = 0; j2 < 8; ++j2) {
        float4 v = px[j2];
        x[4 * j2 + 0] = v.x; x[4 * j2 + 1] = v.y;
        x[4 * j2 + 2] = v.z; x[4 * j2 + 3] = v.w;
    }

    f32x16 acc0[4], acc1[4];
#pragma unroll
    for (int j = 0; j < 4; ++j)
#pragma unroll
        for (int r = 0; r < 16; ++r) { acc0[j][r] = 0.f; acc1[j][r] = 0.f; }

    doChunk<0>(x, sA4, sB4, PsiF4, acc0, acc1, l, w, q, rbg, r32, r0, c0);
    doChunk<1>(x, sA4, sB4, PsiF4, acc0, acc1, l, w, q, rbg, r32, r0, c0);
    doChunk<2>(x, sA4, sB4, PsiF4, acc0, acc1, l, w, q, rbg, r32, r0, c0);
    doChunk<3>(x, sA4, sB4, PsiF4, acc0, acc1, l, w, q, rbg, r32, r0, c0);
    doChunk<4>(x, sA4, sB4, PsiF4, acc0, acc1, l, w, q, rbg, r32, r0, c0);
    doChunk<5>(x, sA4, sB4, PsiF4, acc0, acc1, l, w, q, rbg, r32, r0, c0);
    doChunk<6>(x, sA4, sB4, PsiF4, acc0, acc1, l, w, q, rbg, r32, r0, c0);
    doChunk<7>(x, sA4, sB4, PsiF4, acc0, acc1, l, w, q, rbg, r32, r0, c0);
    doChunk<8>(x, sA4, sB4, PsiF4, acc0, acc1, l, w, q, rbg, r32, r0, c0);

    // epilogue: add kc2, row-wise LSE over 256 cols (two 128-col halves)
    float kcv[4];
#pragma unroll
    for (int j = 0; j < 4; ++j) kcv[j] = kc2[(c0 + j) * 32 + (l & 31)];

    __syncthreads();                       // all sA readers done before overlay
    epiHalf(acc0, kcv, r0,     l, w & 1, sM, sS);
    epiHalf(acc1, kcv, r0 + 1, l, w & 1, sM, sS);
    __syncthreads();

    if (t < 128) {
        const float m0 = sM[t][0], m1 = sM[t][1];
        const float M = fmaxf(m0, m1);
        const float Sv = sS[t][0] * __expf(m0 - M) + sS[t][1] * __expf(m1 - M);
        out[(size_t)blockIdx.x * 128 + t] = M + __logf(Sv) - thr[0];
    }
}

extern "C" void kernel_launch(void* const* d_in, const int* in_sizes, int n_in,
                              void* d_out, int out_size, void* d_ws, size_t ws_size,
                              hipStream_t stream) {
    const float* points  = (const float*)d_in[0];
    const float* centers = (const float*)d_in[1];
    const float* covs    = (const float*)d_in[2];
    const float* weights = (const float*)d_in[3];
    const float* thr     = (const float*)d_in[4];
    float* out = (float*)d_out;

    unsigned short* PsiF = (unsigned short*)d_ws;
    float* kc2 = (float*)((char*)d_ws + PSIF_BYTES);

    gmm_pre<<<KCOMP, 256, 0, stream>>>(covs, centers, weights, PsiF, kc2);
    gmm_mfma<<<NPTS / 128, 256, 0, stream>>>(points, PsiF, kc2, thr, out);
}

// Round 3
// 147.335 us; speedup vs baseline: 1.0052x; 1.0052x over previous
//
#include <hip/hip_runtime.h>
#include <math.h>

#define NPTS 131072
#define KCOMP 256
#define DIM 32
#define NREAL 560                 // 528 tight-packed quad + 32 linear
#define NCH 18                    // 32-feature chunks: 17 full + 1 half (16)
#define PSIF_BYTES 294912         // 18 chunks * 1024 granules * 16 B
#define WS_NEED (PSIF_BYTES + KCOMP * 4)

typedef __attribute__((ext_vector_type(8))) short short8;
typedef __attribute__((ext_vector_type(16))) float f32x16;

__device__ __forceinline__ unsigned short f2bf(float v) {
    unsigned u = __float_as_uint(v);
    u += 0x7fffu + ((u >> 16) & 1u);   // RNE
    return (unsigned short)(u >> 16);
}

// pack two f32 -> two bf16 (lo | hi<<16). RTN (+0x8000) + byte-perm: 3 ops.
__device__ __forceinline__ unsigned pkbf(float lo, float hi) {
#if __has_builtin(__builtin_amdgcn_perm)
    const unsigned a = __float_as_uint(hi) + 0x8000u;
    const unsigned b = __float_as_uint(lo) + 0x8000u;
    return __builtin_amdgcn_perm(a, b, 0x07060302u);
#else
    return (unsigned)f2bf(lo) | ((unsigned)f2bf(hi) << 16);
#endif
}

// async global->LDS DMA, 16 B/lane; LDS dest = wave-uniform base + lane*16.
__device__ __forceinline__ void dma16(const uint4* g, uint4* s) {
    __builtin_amdgcn_global_load_lds(
        (const __attribute__((address_space(1))) void*)g,
        (__attribute__((address_space(3))) void*)s, 16, 0, 0);
}

// ---- compile-time feature decode: TIGHT triangular packing ----------------
// p in [0,528): (d,f) pairs, f>=d, row-major (row d has 32-d entries).
// p in [528,560): linear features (index p-528).
constexpr int PfxT(int d) { return 32 * d - (d * (d - 1)) / 2; }
constexpr int rowT(int p) { int d = 0; while (d < 31 && PfxT(d + 1) <= p) ++d; return d; }
constexpr int colT(int p) { return rowT(p) + (p - PfxT(rowT(p))); }

template<int P, int J>
__device__ __forceinline__ float genOne(const float (&x)[DIM]) {
    constexpr int p = P + J;
    if constexpr (p >= NREAL) {
        return 0.f;
    } else if constexpr (p >= 528) {
        return x[p - 528];
    } else {
        constexpr int d = rowT(p);
        constexpr int f = colT(p);
        static_assert(d >= 0 && d < 32 && f >= d && f < 32, "bad feature map");
        return x[d] * x[f];
    }
}

// ---------------------------------------------------------------------------
// Precompute: Psi column k scattered into frag-ordered PsiF (bf16), kc2 fp32.
// ---------------------------------------------------------------------------
__global__ __launch_bounds__(256) void gmm_pre(
    const float* __restrict__ S,
    const float* __restrict__ centers,
    const float* __restrict__ weights,
    unsigned short* __restrict__ PsiF,
    float* __restrict__ kc2)
{
    __shared__ float Sl[DIM][DIM + 1];
    __shared__ float As[DIM][DIM + 1];
    __shared__ float cl[DIM], ml[DIM];
    __shared__ float red[256];

    const int k = blockIdx.x, tid = threadIdx.x;

    for (int idx = tid; idx < DIM * DIM; idx += 256)
        Sl[idx >> 5][idx & 31] = S[(size_t)k * DIM * DIM + idx];
    if (tid < DIM) cl[tid] = centers[k * DIM + tid];
    __syncthreads();

    // A = S S^T
    for (int idx = tid; idx < DIM * DIM; idx += 256) {
        const int d = idx >> 5, f = idx & 31;
        float a = 0.f;
#pragma unroll
        for (int e = 0; e < DIM; ++e) a = fmaf(Sl[d][e], Sl[f][e], a);
        As[d][f] = a;
    }
    __syncthreads();

    if (tid < DIM) {
        float mv = 0.f;
#pragma unroll
        for (int f = 0; f < DIM; ++f) mv = fmaf(As[tid][f], cl[f], mv);
        ml[tid] = mv;
    }
    __syncthreads();

    // scatter Psi column k into frag positions (reads As diag+upper, ml).
    for (int p = tid; p < NREAL; p += 256) {
        float val;
        if (p < 528) {
            int d = 0, pr = 0;
            while (pr + (32 - d) <= p) { pr += (32 - d); ++d; }
            const int f = d + (p - pr);
            val = (f == d) ? -0.5f * As[d][d] : -As[d][f];
        } else {
            val = ml[p - 528];
        }
        const int c = p >> 6, kk = p & 63;
        const int s = kk >> 4, qq = (kk >> 3) & 1, j = kk & 7;
        const int ct = k >> 5, ll = qq * 32 + (k & 31);
        const int g = c * 2048 + (s * 8 + ct) * 64 + ll;
        PsiF[(size_t)g * 8 + j] = f2bf(val);
    }

    red[tid] = fabsf(weights[tid]);          // K == 256 == blockDim
    __syncthreads();                          // also fences As/ml reads above
    for (int off = 128; off > 0; off >>= 1) {
        if (tid < off) red[tid] += red[tid + off];
        __syncthreads();
    }
    const float wsum = red[0];

    // SPD Gaussian elimination: 1 barrier/step, logdet(A) = sum log(pivot_j).
    for (int j = 0; j < DIM - 1; ++j) {
        const float inv = 1.0f / As[j][j];
        for (int idx = tid; idx < DIM * DIM; idx += 256) {
            const int r = idx >> 5, c = idx & 31;
            if (r > j && c > j)
                As[r][c] = fmaf(-As[r][j] * inv, As[j][c], As[r][c]);
        }
        __syncthreads();
    }

    if (tid < DIM) red[tid] = __logf(As[tid][tid]);   // pivots > 0 (SPD)
    __syncthreads();
    if (tid == 0) {
        float sl = 0.f;
        for (int j = 0; j < DIM; ++j) sl += red[j];
        float cac = 0.f;
        for (int d2 = 0; d2 < DIM; ++d2) cac = fmaf(ml[d2], cl[d2], cac);
        kc2[k] = __logf(fabsf(weights[k])) - __logf(wsum + 1e-30f)
               + 0.5f * sl - 0.5f * cac;
    }
}

// ---------------------------------------------------------------------------
// Main MFMA kernel, 32-feature chunks, BOTH operands double-buffered:
// per chunk one straight-line body {DMA(c+1) issue | gen(c+1)->sA-alt |
// MFMA(c)} + ONE __syncthreads (its vmcnt(0)/lgkm(0) drain has a full chunk
// of cover). No phase serialization between gen (VALU) and MFMA (matrix pipe).
// LDS 48 KB; occupancy pinned by registers (acc=128 AGPR) at 2 blocks/CU.
// ---------------------------------------------------------------------------
template<int P>
__device__ __forceinline__ void genQuad(const float (&x)[DIM], float* v) {
    v[0] = genOne<P, 0>(x);
    v[1] = genOne<P, 1>(x);
    v[2] = genOne<P, 2>(x);
    v[3] = genOne<P, 3>(x);
}

// site SS (8 features) of 32-feature chunk CH -> sA buffer (CH&1)
template<int CH, int SS>
__device__ __forceinline__ void genSite(const float (&x)[DIM], uint4* base,
                                        int rbg, int r32) {
    float v[8];
    genQuad<CH * 32 + SS * 8>(x, v);
    genQuad<CH * 32 + SS * 8 + 4>(x, v + 4);
    uint4 u;
    u.x = pkbf(v[0], v[1]);
    u.y = pkbf(v[2], v[3]);
    u.z = pkbf(v[4], v[5]);
    u.w = pkbf(v[6], v[7]);
    base[(SS >> 1) * 256 + rbg * 64 + (SS & 1) * 32 + r32] = u;
}

template<int CH>
__device__ __forceinline__ void genChunk(const float (&x)[DIM], uint4* sA4,
                                         int q, int rbg, int r32) {
    uint4* base = sA4 + (CH & 1) * 512;
    if (q == 0) {
        genSite<CH, 0>(x, base, rbg, r32);
        if constexpr (CH < 17) genSite<CH, 2>(x, base, rbg, r32);
    } else {
        genSite<CH, 1>(x, base, rbg, r32);
        if constexpr (CH < 17) genSite<CH, 3>(x, base, rbg, r32);
    }
}

template<int C>
__device__ __forceinline__ void doChunk(const float (&x)[DIM],
    uint4* sA4, uint4* sB4, const uint4* __restrict__ PsiF4,
    f32x16 (&acc0)[4], f32x16 (&acc1)[4],
    int l, int w, int q, int rbg, int r32, int r0, int c0)
{
    // entry (certified by previous barrier): DMA(C) landed in sB[C&1],
    // gen(C) complete in sA[C&1]; sB[(C+1)&1] free (chunk C-1 readers done).

    // issue DMA for chunk C+1 (drained by this chunk's end barrier)
    if constexpr (C + 1 < NCH) {
        constexpr int NI = (C + 1 == 17) ? 2 : 4;   // 512-granule last chunk
        const uint4* src = PsiF4 + (C + 1) * 1024 + w * 64 + l;
        uint4* dst = sB4 + ((C + 1) & 1) * 1024 + w * 64 + l;
#pragma unroll
        for (int i = 0; i < NI; ++i) dma16(src + i * 256, dst + i * 256);
    }

    // gen next chunk's A into the other sA buffer (VALU; overlaps MFMA below)
    if constexpr (C + 1 < NCH) genChunk<C + 1>(x, sA4, q, rbg, r32);

    // MFMA on current chunk
    constexpr int NS = (C < 17) ? 2 : 1;            // K16-steps in this chunk
    const uint4* aa = sA4 + (C & 1) * 512;
    const uint4* bb = sB4 + (C & 1) * 1024;
#pragma unroll
    for (int s = 0; s < NS; ++s) {
        short8 a0 = __builtin_bit_cast(short8, aa[(s * 4 + r0) * 64 + l]);
        short8 a1 = __builtin_bit_cast(short8, aa[(s * 4 + r0 + 1) * 64 + l]);
#pragma unroll
        for (int j = 0; j < 4; ++j) {
            short8 b = __builtin_bit_cast(short8, bb[(s * 8 + c0 + j) * 64 + l]);
            acc0[j] = __builtin_amdgcn_mfma_f32_32x32x16_bf16(a0, b, acc0[j], 0, 0, 0);
            acc1[j] = __builtin_amdgcn_mfma_f32_32x32x16_bf16(a1, b, acc1[j], 0, 0, 0);
        }
    }

    __syncthreads();   // drains DMA(C+1) (full-chunk cover) + gen(C+1) writes
}

__device__ __forceinline__ void epiHalf(const f32x16 (&acc)[4], const float (&kcv)[4],
    int rblock, int l, int whalf, float (*sM)[2], float (*sS)[2])
{
#pragma unroll
    for (int rg = 0; rg < 16; ++rg) {
        float vals[4], m = -INFINITY;
#pragma unroll
        for (int j = 0; j < 4; ++j) { vals[j] = acc[j][rg] + kcv[j]; m = fmaxf(m, vals[j]); }
#pragma unroll
        for (int mask = 1; mask < 32; mask <<= 1) m = fmaxf(m, __shfl_xor(m, mask, 64));
        float sv = 0.f;
#pragma unroll
        for (int j = 0; j < 4; ++j) sv += __expf(vals[j] - m);
#pragma unroll
        for (int mask = 1; mask < 32; mask <<= 1) sv += __shfl_xor(sv, mask, 64);
        if ((l & 31) == 0) {
            const int R = rblock * 32 + (rg & 3) + 8 * (rg >> 2) + 4 * (l >> 5);
            sM[R][whalf] = m; sS[R][whalf] = sv;
        }
    }
}

__global__ __launch_bounds__(256, 2) void gmm_mfma(
    const float* __restrict__ points,
    const unsigned short* __restrict__ PsiF,
    const float* __restrict__ kc2,
    const float* __restrict__ thr,
    float* __restrict__ out)
{
    __shared__ uint4 sA4[1024];          // 16 KB: A double buffer (2 x 8 KB)
    __shared__ uint4 sB4[2048];          // 32 KB: B double buffer (2 x 16 KB)
    // epilogue scratch overlaid on sA4 (after final barrier): sM 1 KB, sS 1 KB
    float (*sM)[2] = (float (*)[2])sA4;
    float (*sS)[2] = (float (*)[2])(sA4 + 64);

    const int t = threadIdx.x;
    const int w = t >> 6, l = t & 63;
    const int row = t & 127, q = t >> 7;           // gen role: 2 threads/row
    const int rbg = row >> 5, r32 = row & 31;
    const int r0 = (w >> 1) * 2, c0 = (w & 1) * 4; // mfma wave tile: 64r x 128c

    const uint4* PsiF4 = (const uint4*)PsiF;

    // prologue DMA: chunk 0's B into buffer 0 (covered by x-load + init + gen)
    {
        const uint4* src = PsiF4 + w * 64 + l;
        uint4* dst = sB4 + w * 64 + l;
#pragma unroll
        for (int i = 0; i < 4; ++i) dma16(src + i * 256, dst + i * 256);
    }

    float x[DIM];
    const float4* px = (const float4*)(points + ((size_t)blockIdx.x * 128 + row) * DIM);
#pragma unroll
    for (int j2 = 0; j2 < 8; ++j2) {
        float4 v = px[j2];
        x[4 * j2 + 0] = v.x; x[4 * j2 + 1] = v.y;
        x[4 * j2 + 2] = v.z; x[4 * j2 + 3] = v.w;
    }

    f32x16 acc0[4], acc1[4];
#pragma unroll
    for (int j = 0; j < 4; ++j)
#pragma unroll
        for (int r = 0; r < 16; ++r) { acc0[j][r] = 0.f; acc1[j][r] = 0.f; }

    genChunk<0>(x, sA4, q, rbg, r32);
    __syncthreads();               // sA[0] ready; drains DMA(0)

    doChunk<0>(x, sA4, sB4, PsiF4, acc0, acc1, l, w, q, rbg, r32, r0, c0);
    doChunk<1>(x, sA4, sB4, PsiF4, acc0, acc1, l, w, q, rbg, r32, r0, c0);
    doChunk<2>(x, sA4, sB4, PsiF4, acc0, acc1, l, w, q, rbg, r32, r0, c0);
    doChunk<3>(x, sA4, sB4, PsiF4, acc0, acc1, l, w, q, rbg, r32, r0, c0);
    doChunk<4>(x, sA4, sB4, PsiF4, acc0, acc1, l, w, q, rbg, r32, r0, c0);
    doChunk<5>(x, sA4, sB4, PsiF4, acc0, acc1, l, w, q, rbg, r32, r0, c0);
    doChunk<6>(x, sA4, sB4, PsiF4, acc0, acc1, l, w, q, rbg, r32, r0, c0);
    doChunk<7>(x, sA4, sB4, PsiF4, acc0, acc1, l, w, q, rbg, r32, r0, c0);
    doChunk<8>(x, sA4, sB4, PsiF4, acc0, acc1, l, w, q, rbg, r32, r0, c0);
    doChunk<9>(x, sA4, sB4, PsiF4, acc0, acc1, l, w, q, rbg, r32, r0, c0);
    doChunk<10>(x, sA4, sB4, PsiF4, acc0, acc1, l, w, q, rbg, r32, r0, c0);
    doChunk<11>(x, sA4, sB4, PsiF4, acc0, acc1, l, w, q, rbg, r32, r0, c0);
    doChunk<12>(x, sA4, sB4, PsiF4, acc0, acc1, l, w, q, rbg, r32, r0, c0);
    doChunk<13>(x, sA4, sB4, PsiF4, acc0, acc1, l, w, q, rbg, r32, r0, c0);
    doChunk<14>(x, sA4, sB4, PsiF4, acc0, acc1, l, w, q, rbg, r32, r0, c0);
    doChunk<15>(x, sA4, sB4, PsiF4, acc0, acc1, l, w, q, rbg, r32, r0, c0);
    doChunk<16>(x, sA4, sB4, PsiF4, acc0, acc1, l, w, q, rbg, r32, r0, c0);
    doChunk<17>(x, sA4, sB4, PsiF4, acc0, acc1, l, w, q, rbg, r32, r0, c0);

    // epilogue: add kc2, row-wise LSE over 256 cols (two 128-col halves)
    float kcv[4];
#pragma unroll
    for (int j = 0; j < 4; ++j) kcv[j] = kc2[(c0 + j) * 32 + (l & 31)];

    // chunk 17's end barrier already separates main loop from the overlay
    epiHalf(acc0, kcv, r0,     l, w & 1, sM, sS);
    epiHalf(acc1, kcv, r0 + 1, l, w & 1, sM, sS);
    __syncthreads();

    if (t < 128) {
        const float m0 = sM[t][0], m1 = sM[t][1];
        const float M = fmaxf(m0, m1);
        const float Sv = sS[t][0] * __expf(m0 - M) + sS[t][1] * __expf(m1 - M);
        out[(size_t)blockIdx.x * 128 + t] = M + __logf(Sv) - thr[0];
    }
}

extern "C" void kernel_launch(void* const* d_in, const int* in_sizes, int n_in,
                              void* d_out, int out_size, void* d_ws, size_t ws_size,
                              hipStream_t stream) {
    const float* points  = (const float*)d_in[0];
    const float* centers = (const float*)d_in[1];
    const float* covs    = (const float*)d_in[2];
    const float* weights = (const float*)d_in[3];
    const float* thr     = (const float*)d_in[4];
    float* out = (float*)d_out;

    unsigned short* PsiF = (unsigned short*)d_ws;
    float* kc2 = (float*)((char*)d_ws + PSIF_BYTES);

    gmm_pre<<<KCOMP, 256, 0, stream>>>(covs, centers, weights, PsiF, kc2);
    gmm_mfma<<<NPTS / 128, 256, 0, stream>>>(points, PsiF, kc2, thr, out);
}

// Round 4
// 139.308 us; speedup vs baseline: 1.0631x; 1.0576x over previous
//
#include <hip/hip_runtime.h>
#include <math.h>

#define NPTS 131072
#define KCOMP 256
#define DIM 32
#define NREAL 560                 // 528 tight-packed quad + 32 linear
#define NCH 18                    // 32-feature chunks: 17 full + 1 half (16)
#define PSIF_BYTES 294912         // 18 chunks * 1024 granules * 16 B
#define WS_NEED (PSIF_BYTES + KCOMP * 4)

typedef __attribute__((ext_vector_type(8))) short short8;
typedef __attribute__((ext_vector_type(16))) float f32x16;

__device__ __forceinline__ unsigned short f2bf(float v) {
    unsigned u = __float_as_uint(v);
    u += 0x7fffu + ((u >> 16) & 1u);   // RNE
    return (unsigned short)(u >> 16);
}

// pack two f32 -> two bf16 (lo | hi<<16). RTN (+0x8000) + byte-perm: 3 ops.
__device__ __forceinline__ unsigned pkbf(float lo, float hi) {
#if __has_builtin(__builtin_amdgcn_perm)
    const unsigned a = __float_as_uint(hi) + 0x8000u;
    const unsigned b = __float_as_uint(lo) + 0x8000u;
    return __builtin_amdgcn_perm(a, b, 0x07060302u);
#else
    return (unsigned)f2bf(lo) | ((unsigned)f2bf(hi) << 16);
#endif
}

// async global->LDS DMA, 16 B/lane; LDS dest = wave-uniform base + lane*16.
__device__ __forceinline__ void dma16(const uint4* g, uint4* s) {
    __builtin_amdgcn_global_load_lds(
        (const __attribute__((address_space(1))) void*)g,
        (__attribute__((address_space(3))) void*)s, 16, 0, 0);
}

// ---- compile-time feature decode: TIGHT triangular packing ----------------
// p in [0,528): (d,f) pairs, f>=d, row-major (row d has 32-d entries).
// p in [528,560): linear features (index p-528).
constexpr int PfxT(int d) { return 32 * d - (d * (d - 1)) / 2; }
constexpr int rowT(int p) { int d = 0; while (d < 31 && PfxT(d + 1) <= p) ++d; return d; }
constexpr int colT(int p) { return rowT(p) + (p - PfxT(rowT(p))); }

template<int P, int J>
__device__ __forceinline__ float genOne(const float (&x)[DIM]) {
    constexpr int p = P + J;
    if constexpr (p >= NREAL) {
        return 0.f;
    } else if constexpr (p >= 528) {
        return x[p - 528];
    } else {
        constexpr int d = rowT(p);
        constexpr int f = colT(p);
        static_assert(d >= 0 && d < 32 && f >= d && f < 32, "bad feature map");
        return x[d] * x[f];
    }
}

// ---------------------------------------------------------------------------
// Precompute: Psi column k scattered into frag-ordered PsiF (bf16), kc2 fp32.
// ---------------------------------------------------------------------------
__global__ __launch_bounds__(256) void gmm_pre(
    const float* __restrict__ S,
    const float* __restrict__ centers,
    const float* __restrict__ weights,
    unsigned short* __restrict__ PsiF,
    float* __restrict__ kc2)
{
    __shared__ float Sl[DIM][DIM + 1];
    __shared__ float As[DIM][DIM + 1];
    __shared__ float cl[DIM], ml[DIM];
    __shared__ float red[256];

    const int k = blockIdx.x, tid = threadIdx.x;

    for (int idx = tid; idx < DIM * DIM; idx += 256)
        Sl[idx >> 5][idx & 31] = S[(size_t)k * DIM * DIM + idx];
    if (tid < DIM) cl[tid] = centers[k * DIM + tid];
    __syncthreads();

    // A = S S^T
    for (int idx = tid; idx < DIM * DIM; idx += 256) {
        const int d = idx >> 5, f = idx & 31;
        float a = 0.f;
#pragma unroll
        for (int e = 0; e < DIM; ++e) a = fmaf(Sl[d][e], Sl[f][e], a);
        As[d][f] = a;
    }
    __syncthreads();

    if (tid < DIM) {
        float mv = 0.f;
#pragma unroll
        for (int f = 0; f < DIM; ++f) mv = fmaf(As[tid][f], cl[f], mv);
        ml[tid] = mv;
    }
    __syncthreads();

    // scatter Psi column k into frag positions (reads As diag+upper, ml).
    for (int p = tid; p < NREAL; p += 256) {
        float val;
        if (p < 528) {
            int d = 0, pr = 0;
            while (pr + (32 - d) <= p) { pr += (32 - d); ++d; }
            const int f = d + (p - pr);
            val = (f == d) ? -0.5f * As[d][d] : -As[d][f];
        } else {
            val = ml[p - 528];
        }
        const int c = p >> 6, kk = p & 63;
        const int s = kk >> 4, qq = (kk >> 3) & 1, j = kk & 7;
        const int ct = k >> 5, ll = qq * 32 + (k & 31);
        const int g = c * 2048 + (s * 8 + ct) * 64 + ll;
        PsiF[(size_t)g * 8 + j] = f2bf(val);
    }

    red[tid] = fabsf(weights[tid]);          // K == 256 == blockDim
    __syncthreads();                          // also fences As/ml reads above
    for (int off = 128; off > 0; off >>= 1) {
        if (tid < off) red[tid] += red[tid + off];
        __syncthreads();
    }
    const float wsum = red[0];

    // SPD Gaussian elimination: 1 barrier/step, logdet(A) = sum log(pivot_j).
    for (int j = 0; j < DIM - 1; ++j) {
        const float inv = 1.0f / As[j][j];
        for (int idx = tid; idx < DIM * DIM; idx += 256) {
            const int r = idx >> 5, c = idx & 31;
            if (r > j && c > j)
                As[r][c] = fmaf(-As[r][j] * inv, As[j][c], As[r][c]);
        }
        __syncthreads();
    }

    if (tid < DIM) red[tid] = __logf(As[tid][tid]);   // pivots > 0 (SPD)
    __syncthreads();
    if (tid == 0) {
        float sl = 0.f;
        for (int j = 0; j < DIM; ++j) sl += red[j];
        float cac = 0.f;
        for (int d2 = 0; d2 < DIM; ++d2) cac = fmaf(ml[d2], cl[d2], cac);
        kc2[k] = __logf(fabsf(weights[k])) - __logf(wsum + 1e-30f)
               + 0.5f * sl - 0.5f * cac;
    }
}

// ---------------------------------------------------------------------------
// Main MFMA kernel: 512 threads / 8 waves per 128-row block. Wave tile
// 32r x 128c -> acc = 4 x f32x16 = 64 AGPR/thread; target <=128 total regs
// -> 4 waves/SIMD, 2 blocks (16 waves)/CU: 2x the occupancy of the 256-thread
// version (which was register-capped at 2 waves/SIMD by its 128-AGPR acc).
// Per chunk: {DMA(c+1) | gen(c+1)->sA-alt | MFMA(c)} + one __syncthreads.
// LDS 48 KB (sA 2x8 KB + sB 2x16 KB).
// ---------------------------------------------------------------------------
template<int P>
__device__ __forceinline__ void genQuad(const float (&x)[DIM], float* v) {
    v[0] = genOne<P, 0>(x);
    v[1] = genOne<P, 1>(x);
    v[2] = genOne<P, 2>(x);
    v[3] = genOne<P, 3>(x);
}

// site SS (8 features) of 32-feature chunk CH -> sA buffer (CH&1)
template<int CH, int SS>
__device__ __forceinline__ void genSite(const float (&x)[DIM], uint4* base,
                                        int rbg, int r32) {
    float v[8];
    genQuad<CH * 32 + SS * 8>(x, v);
    genQuad<CH * 32 + SS * 8 + 4>(x, v + 4);
    uint4 u;
    u.x = pkbf(v[0], v[1]);
    u.y = pkbf(v[2], v[3]);
    u.z = pkbf(v[4], v[5]);
    u.w = pkbf(v[6], v[7]);
    base[(SS >> 1) * 256 + rbg * 64 + (SS & 1) * 32 + r32] = u;
}

// q = t>>7 is wave-uniform: wave handles exactly one site -> no divergence.
template<int CH>
__device__ __forceinline__ void genChunk(const float (&x)[DIM], uint4* sA4,
                                         int q, int rbg, int r32) {
    uint4* base = sA4 + (CH & 1) * 512;
    if constexpr (CH < 17) {
        if (q == 0)      genSite<CH, 0>(x, base, rbg, r32);
        else if (q == 1) genSite<CH, 1>(x, base, rbg, r32);
        else if (q == 2) genSite<CH, 2>(x, base, rbg, r32);
        else             genSite<CH, 3>(x, base, rbg, r32);
    } else {
        if (q == 0)      genSite<CH, 0>(x, base, rbg, r32);
        else if (q == 1) genSite<CH, 1>(x, base, rbg, r32);
        // q >= 2 idle: chunk 17 has only 16 features (2 sites)
    }
}

template<int C>
__device__ __forceinline__ void doChunk(const float (&x)[DIM],
    uint4* sA4, uint4* sB4, const uint4* __restrict__ PsiF4,
    f32x16 (&acc)[4],
    int l, int w, int q, int rbg, int r32, int rb, int c0)
{
    // entry (certified by previous barrier): DMA(C) landed in sB[C&1],
    // gen(C) complete in sA[C&1]; sB[(C+1)&1] free (chunk C-1 readers done).

    // issue DMA for chunk C+1 (drained by this chunk's end barrier)
    if constexpr (C + 1 < NCH) {
        constexpr int NI = (C + 1 == 17) ? 1 : 2;   // 512-granule last chunk
        const uint4* src = PsiF4 + (C + 1) * 1024 + w * 64 + l;
        uint4* dst = sB4 + ((C + 1) & 1) * 1024 + w * 64 + l;
#pragma unroll
        for (int i = 0; i < NI; ++i) dma16(src + i * 512, dst + i * 512);
    }

    // gen next chunk's A into the other sA buffer (VALU; overlaps MFMA below)
    if constexpr (C + 1 < NCH) genChunk<C + 1>(x, sA4, q, rbg, r32);

    // MFMA on current chunk: wave tile 32r x 128c
    constexpr int NS = (C < 17) ? 2 : 1;            // K16-steps in this chunk
    const uint4* aa = sA4 + (C & 1) * 512;
    const uint4* bb = sB4 + (C & 1) * 1024;
#pragma unroll
    for (int s = 0; s < NS; ++s) {
        short8 a = __builtin_bit_cast(short8, aa[(s * 4 + rb) * 64 + l]);
#pragma unroll
        for (int j = 0; j < 4; ++j) {
            short8 b = __builtin_bit_cast(short8, bb[(s * 8 + c0 + j) * 64 + l]);
            acc[j] = __builtin_amdgcn_mfma_f32_32x32x16_bf16(a, b, acc[j], 0, 0, 0);
        }
    }

    __syncthreads();   // drains DMA(C+1) (full-chunk cover) + gen(C+1) writes
}

__device__ __forceinline__ void epiHalf(const f32x16 (&acc)[4], const float (&kcv)[4],
    int rblock, int l, int whalf, float (*sM)[2], float (*sS)[2])
{
#pragma unroll
    for (int rg = 0; rg < 16; ++rg) {
        float vals[4], m = -INFINITY;
#pragma unroll
        for (int j = 0; j < 4; ++j) { vals[j] = acc[j][rg] + kcv[j]; m = fmaxf(m, vals[j]); }
#pragma unroll
        for (int mask = 1; mask < 32; mask <<= 1) m = fmaxf(m, __shfl_xor(m, mask, 64));
        float sv = 0.f;
#pragma unroll
        for (int j = 0; j < 4; ++j) sv += __expf(vals[j] - m);
#pragma unroll
        for (int mask = 1; mask < 32; mask <<= 1) sv += __shfl_xor(sv, mask, 64);
        if ((l & 31) == 0) {
            const int R = rblock * 32 + (rg & 3) + 8 * (rg >> 2) + 4 * (l >> 5);
            sM[R][whalf] = m; sS[R][whalf] = sv;
        }
    }
}

__global__ __launch_bounds__(512, 4) void gmm_mfma(
    const float* __restrict__ points,
    const unsigned short* __restrict__ PsiF,
    const float* __restrict__ kc2,
    const float* __restrict__ thr,
    float* __restrict__ out)
{
    __shared__ uint4 sA4[1024];          // 16 KB: A double buffer (2 x 8 KB)
    __shared__ uint4 sB4[2048];          // 32 KB: B double buffer (2 x 16 KB)
    // epilogue scratch overlaid on sA4 (after final barrier): sM 1 KB, sS 1 KB
    float (*sM)[2] = (float (*)[2])sA4;
    float (*sS)[2] = (float (*)[2])(sA4 + 64);

    const int t = threadIdx.x;
    const int w = t >> 6, l = t & 63;
    const int row = t & 127, q = t >> 7;           // gen role: wave-uniform site
    const int rbg = row >> 5, r32 = row & 31;
    const int rb = w >> 1, c0 = (w & 1) * 4;       // mfma wave tile: 32r x 128c

    const uint4* PsiF4 = (const uint4*)PsiF;

    // prologue DMA: chunk 0's B into buffer 0 (covered by x-load + init + gen)
    {
        const uint4* src = PsiF4 + w * 64 + l;
        uint4* dst = sB4 + w * 64 + l;
        dma16(src, dst);
        dma16(src + 512, dst + 512);
    }

    float x[DIM];
    const float4* px = (const float4*)(points + ((size_t)blockIdx.x * 128 + row) * DIM);
#pragma unroll
    for (int j2 = 0; j2 < 8; ++j2) {
        float4 v = px[j2];
        x[4 * j2 + 0] = v.x; x[4 * j2 + 1] = v.y;
        x[4 * j2 + 2] = v.z; x[4 * j2 + 3] = v.w;
    }

    f32x16 acc[4];
#pragma unroll
    for (int j = 0; j < 4; ++j)
#pragma unroll
        for (int r = 0; r < 16; ++r) acc[j][r] = 0.f;

    genChunk<0>(x, sA4, q, rbg, r32);
    __syncthreads();               // sA[0] ready; drains DMA(0)

    doChunk<0>(x, sA4, sB4, PsiF4, acc, l, w, q, rbg, r32, rb, c0);
    doChunk<1>(x, sA4, sB4, PsiF4, acc, l, w, q, rbg, r32, rb, c0);
    doChunk<2>(x, sA4, sB4, PsiF4, acc, l, w, q, rbg, r32, rb, c0);
    doChunk<3>(x, sA4, sB4, PsiF4, acc, l, w, q, rbg, r32, rb, c0);
    doChunk<4>(x, sA4, sB4, PsiF4, acc, l, w, q, rbg, r32, rb, c0);
    doChunk<5>(x, sA4, sB4, PsiF4, acc, l, w, q, rbg, r32, rb, c0);
    doChunk<6>(x, sA4, sB4, PsiF4, acc, l, w, q, rbg, r32, rb, c0);
    doChunk<7>(x, sA4, sB4, PsiF4, acc, l, w, q, rbg, r32, rb, c0);
    doChunk<8>(x, sA4, sB4, PsiF4, acc, l, w, q, rbg, r32, rb, c0);
    doChunk<9>(x, sA4, sB4, PsiF4, acc, l, w, q, rbg, r32, rb, c0);
    doChunk<10>(x, sA4, sB4, PsiF4, acc, l, w, q, rbg, r32, rb, c0);
    doChunk<11>(x, sA4, sB4, PsiF4, acc, l, w, q, rbg, r32, rb, c0);
    doChunk<12>(x, sA4, sB4, PsiF4, acc, l, w, q, rbg, r32, rb, c0);
    doChunk<13>(x, sA4, sB4, PsiF4, acc, l, w, q, rbg, r32, rb, c0);
    doChunk<14>(x, sA4, sB4, PsiF4, acc, l, w, q, rbg, r32, rb, c0);
    doChunk<15>(x, sA4, sB4, PsiF4, acc, l, w, q, rbg, r32, rb, c0);
    doChunk<16>(x, sA4, sB4, PsiF4, acc, l, w, q, rbg, r32, rb, c0);
    doChunk<17>(x, sA4, sB4, PsiF4, acc, l, w, q, rbg, r32, rb, c0);

    // epilogue: add kc2, row-wise LSE over 256 cols (two 128-col halves)
    float kcv[4];
#pragma unroll
    for (int j = 0; j < 4; ++j) kcv[j] = kc2[(c0 + j) * 32 + (l & 31)];

    // chunk 17's end barrier already separates main loop from the overlay
    epiHalf(acc, kcv, rb, l, w & 1, sM, sS);
    __syncthreads();

    if (t < 128) {
        const float m0 = sM[t][0], m1 = sM[t][1];
        const float M = fmaxf(m0, m1);
        const float Sv = sS[t][0] * __expf(m0 - M) + sS[t][1] * __expf(m1 - M);
        out[(size_t)blockIdx.x * 128 + t] = M + __logf(Sv) - thr[0];
    }
}

extern "C" void kernel_launch(void* const* d_in, const int* in_sizes, int n_in,
                              void* d_out, int out_size, void* d_ws, size_t ws_size,
                              hipStream_t stream) {
    const float* points  = (const float*)d_in[0];
    const float* centers = (const float*)d_in[1];
    const float* covs    = (const float*)d_in[2];
    const float* weights = (const float*)d_in[3];
    const float* thr     = (const float*)d_in[4];
    float* out = (float*)d_out;

    unsigned short* PsiF = (unsigned short*)d_ws;
    float* kc2 = (float*)((char*)d_ws + PSIF_BYTES);

    gmm_pre<<<KCOMP, 256, 0, stream>>>(covs, centers, weights, PsiF, kc2);
    gmm_mfma<<<NPTS / 128, 512, 0, stream>>>(points, PsiF, kc2, thr, out);
}